// Round 7
// baseline (129.099 us; speedup 1.0000x reference)
//
#include <hip/hip_runtime.h>
#include <hip/hip_bf16.h>

#define BATCH 8
#define NN    256
#define FIN   128
#define H1    4
#define C1    128
#define HC1   512   // H1*C1
#define NEG_SLOPE 0.2f

__device__ __forceinline__ float lrelu(float v) {
    return v > 0.f ? v : NEG_SLOPE * v;
}
__device__ __forceinline__ float4 f4fma(float s, float4 w, float4 a) {
    a.x = fmaf(s, w.x, a.x); a.y = fmaf(s, w.y, a.y);
    a.z = fmaf(s, w.z, a.z); a.w = fmaf(s, w.w, a.w);
    return a;
}

// ---------------- K1: h1 = x @ W1, fused a_src1/a_dst1 ----------------------
// grid (32 = 16 rowtiles x 2 colhalves, 8), block 256 (4 waves).
// Thread: 4 rows x 4 cols register tile; float4 W1 + float4 LDS reads.
__global__ __launch_bounds__(256, 4)
void gemm1_fused(const float* __restrict__ x, const float* __restrict__ W1,
                 const float* __restrict__ as1, const float* __restrict__ ad1,
                 float* __restrict__ h1, float* __restrict__ a_src,
                 float* __restrict__ a_dst) {
    __shared__ float xs[16][FIN];               // 8 KB
    __shared__ float redS[4][2][4], redD[4][2][4];
    const int bx = blockIdx.x, b = blockIdx.y, t = threadIdx.x;
    const int rt = bx & 15, ch = bx >> 4;       // row-tile, col-half
    const int q = t & 63, rg = t >> 6;          // col-quad in half, row-group(=wave)

    {   // stage 16 rows x 128 = 512 float4
        const float4* xp = (const float4*)(x + ((size_t)b * NN + rt * 16) * FIN);
        float4* x4 = (float4*)xs;
        x4[t] = xp[t];
        x4[t + 256] = xp[t + 256];
    }
    __syncthreads();

    const int col0 = ch * 256 + q * 4;
    float4 a0 = {0,0,0,0}, a1 = {0,0,0,0}, a2 = {0,0,0,0}, a3 = {0,0,0,0};
    const float4* xr0 = (const float4*)&xs[rg * 4 + 0][0];
    const float4* xr1 = (const float4*)&xs[rg * 4 + 1][0];
    const float4* xr2 = (const float4*)&xs[rg * 4 + 2][0];
    const float4* xr3 = (const float4*)&xs[rg * 4 + 3][0];
    #pragma unroll 4
    for (int kq = 0; kq < 32; ++kq) {
        float4 x0 = xr0[kq], x1 = xr1[kq], x2 = xr2[kq], x3 = xr3[kq];
        const float* wb = W1 + (size_t)(kq * 4) * HC1 + col0;
        float4 w0 = *(const float4*)(wb);
        float4 w1 = *(const float4*)(wb + HC1);
        float4 w2 = *(const float4*)(wb + 2 * HC1);
        float4 w3 = *(const float4*)(wb + 3 * HC1);
        a0 = f4fma(x0.x, w0, a0); a0 = f4fma(x0.y, w1, a0);
        a0 = f4fma(x0.z, w2, a0); a0 = f4fma(x0.w, w3, a0);
        a1 = f4fma(x1.x, w0, a1); a1 = f4fma(x1.y, w1, a1);
        a1 = f4fma(x1.z, w2, a1); a1 = f4fma(x1.w, w3, a1);
        a2 = f4fma(x2.x, w0, a2); a2 = f4fma(x2.y, w1, a2);
        a2 = f4fma(x2.z, w2, a2); a2 = f4fma(x2.w, w3, a2);
        a3 = f4fma(x3.x, w0, a3); a3 = f4fma(x3.y, w1, a3);
        a3 = f4fma(x3.z, w2, a3); a3 = f4fma(x3.w, w3, a3);
    }

    const size_t rowbase = (size_t)b * NN + rt * 16 + rg * 4;
    *(float4*)(h1 + (rowbase + 0) * HC1 + col0) = a0;
    *(float4*)(h1 + (rowbase + 1) * HC1 + col0) = a1;
    *(float4*)(h1 + (rowbase + 2) * HC1 + col0) = a2;
    *(float4*)(h1 + (rowbase + 3) * HC1 + col0) = a3;

    // fused a-reductions. Lanes 0-31: head ch*2, lanes 32-63: head ch*2+1.
    float4 asv = *(const float4*)(as1 + col0);
    float4 adv = *(const float4*)(ad1 + col0);
    float s[4], d[4];
    float4 accs[4] = {a0, a1, a2, a3};
    #pragma unroll
    for (int i = 0; i < 4; ++i) {
        s[i] = accs[i].x * asv.x + accs[i].y * asv.y + accs[i].z * asv.z + accs[i].w * asv.w;
        d[i] = accs[i].x * adv.x + accs[i].y * adv.y + accs[i].z * adv.z + accs[i].w * adv.w;
    }
    #pragma unroll
    for (int off = 16; off > 0; off >>= 1) {
        #pragma unroll
        for (int i = 0; i < 4; ++i) {
            s[i] += __shfl_down(s[i], off, 32);
            d[i] += __shfl_down(d[i], off, 32);
        }
    }
    if ((t & 31) == 0) {
        int hh = q >> 5;
        #pragma unroll
        for (int i = 0; i < 4; ++i) { redS[rg][hh][i] = s[i]; redD[rg][hh][i] = d[i]; }
    }
    __syncthreads();
    if (t < 32) {
        int rg2 = t >> 3, hh = (t >> 2) & 1, r = t & 3;
        size_t node = (size_t)b * NN + rt * 16 + rg2 * 4 + r;
        a_src[node * H1 + ch * 2 + hh] = redS[rg2][hh][r];
        a_dst[node * H1 + ch * 2 + hh] = redD[rg2][hh][r];
    }
}

// ---------------- K2: layer-1 softmax + aggregate + bias + relu -------------
// grid (16 dst-tiles, 4 heads, 8 batch), block 512. 16 dsts/block.
// p stored transposed spT[src][dst] (stride 20) -> one b128 read per src.
__global__ __launch_bounds__(512, 4)
void agg1_kernel(const float* __restrict__ h1, const float* __restrict__ a_src,
                 const float* __restrict__ a_dst, const float* __restrict__ b1,
                 float* __restrict__ hrelu) {
    __shared__ float s_as[NN];
    __shared__ float s_ad[16];
    __shared__ float spT[NN][20];      // 20 KB, stride 20 floats (80B, 16B-aligned)
    __shared__ float s_den[16];

    const int b = blockIdx.z, head = blockIdx.y, d0 = blockIdx.x * 16;
    const int t = threadIdx.x;

    if (t < NN) s_as[t] = a_src[(b * NN + t) * H1 + head];
    if (t < 16) s_ad[t] = a_dst[(b * NN + d0 + t) * H1 + head];
    __syncthreads();

    // softmax: 32 threads per dst, 8 srcs each.
    const int d = t >> 5, l = t & 31;
    const float adst = s_ad[d];
    float e[8];
    float mx = -1e30f;
    #pragma unroll
    for (int i = 0; i < 8; ++i) {
        float v = lrelu(s_as[l + i * 32] + adst);
        e[i] = v;
        mx = fmaxf(mx, v);
    }
    #pragma unroll
    for (int off = 16; off > 0; off >>= 1)
        mx = fmaxf(mx, __shfl_down(mx, off, 32));
    mx = __shfl(mx, 0, 32);
    float sum = 0.f;
    #pragma unroll
    for (int i = 0; i < 8; ++i) {
        float p = __expf(e[i] - mx);
        spT[l + i * 32][d] = p;
        sum += p;
    }
    #pragma unroll
    for (int off = 16; off > 0; off >>= 1)
        sum += __shfl_down(sum, off, 32);
    if (l == 0) s_den[d] = sum + 1e-16f;
    __syncthreads();

    // aggregation: c = col, g -> dsts g*4..g*4+3; per src: 1 b32 glob + 1 b128 LDS.
    const int c = t & 127, g = t >> 7;
    float c0 = 0.f, c1 = 0.f, c2 = 0.f, c3 = 0.f;
    const float* hb = h1 + (size_t)(b * NN) * HC1 + head * C1 + c;
    #pragma unroll 4
    for (int src = 0; src < NN; ++src) {
        float hv = hb[(size_t)src * HC1];
        float4 p4 = *(const float4*)&spT[src][g * 4];
        c0 = fmaf(p4.x, hv, c0);
        c1 = fmaf(p4.y, hv, c1);
        c2 = fmaf(p4.z, hv, c2);
        c3 = fmaf(p4.w, hv, c3);
    }
    float accs[4] = {c0, c1, c2, c3};
    const float bias = b1[head * C1 + c];
    #pragma unroll
    for (int j = 0; j < 4; ++j) {
        int dst = d0 + g * 4 + j;
        float v = accs[j] / s_den[g * 4 + j] + bias;
        hrelu[(b * NN + dst) * HC1 + head * C1 + c] = fmaxf(v, 0.f);
    }
}

// ---------------- K3: h2 = hrelu @ W2, fused a_src2/a_dst2 ------------------
// grid (64, 8), block 512. 4 rows/block; K split 4-way; quad-k float4 LDS reads.
__global__ __launch_bounds__(512, 4)
void gemm2_fused(const float* __restrict__ hrelu, const float* __restrict__ W2,
                 const float* __restrict__ as2, const float* __restrict__ ad2,
                 float* __restrict__ h2, float* __restrict__ a_src,
                 float* __restrict__ a_dst) {
    __shared__ float xs[4][HC1];            // 8 KB
    __shared__ float red[3][4][FIN];        // 6 KB
    __shared__ float redS[4][2], redD[4][2];
    const int b = blockIdx.y, r0 = blockIdx.x * 4, t = threadIdx.x;

    ((float4*)xs)[t] = ((const float4*)(hrelu + (size_t)(b * NN + r0) * HC1))[t];
    __syncthreads();

    const int c = t & 127, g = t >> 7;      // g = K-chunk [g*128, g*128+128)
    float acc[4] = {0.f, 0.f, 0.f, 0.f};
    const float4* x40 = (const float4*)&xs[0][g * 128];
    const float4* x41 = (const float4*)&xs[1][g * 128];
    const float4* x42 = (const float4*)&xs[2][g * 128];
    const float4* x43 = (const float4*)&xs[3][g * 128];
    const float* wb = W2 + (size_t)(g * 128) * FIN + c;
    #pragma unroll 4
    for (int kq = 0; kq < 32; ++kq) {
        float4 x0 = x40[kq], x1 = x41[kq], x2 = x42[kq], x3 = x43[kq];
        float w0 = wb[(size_t)(kq * 4 + 0) * FIN];
        float w1 = wb[(size_t)(kq * 4 + 1) * FIN];
        float w2 = wb[(size_t)(kq * 4 + 2) * FIN];
        float w3 = wb[(size_t)(kq * 4 + 3) * FIN];
        acc[0] = fmaf(x0.x, w0, acc[0]); acc[0] = fmaf(x0.y, w1, acc[0]);
        acc[0] = fmaf(x0.z, w2, acc[0]); acc[0] = fmaf(x0.w, w3, acc[0]);
        acc[1] = fmaf(x1.x, w0, acc[1]); acc[1] = fmaf(x1.y, w1, acc[1]);
        acc[1] = fmaf(x1.z, w2, acc[1]); acc[1] = fmaf(x1.w, w3, acc[1]);
        acc[2] = fmaf(x2.x, w0, acc[2]); acc[2] = fmaf(x2.y, w1, acc[2]);
        acc[2] = fmaf(x2.z, w2, acc[2]); acc[2] = fmaf(x2.w, w3, acc[2]);
        acc[3] = fmaf(x3.x, w0, acc[3]); acc[3] = fmaf(x3.y, w1, acc[3]);
        acc[3] = fmaf(x3.z, w2, acc[3]); acc[3] = fmaf(x3.w, w3, acc[3]);
    }
    if (g > 0) {
        #pragma unroll
        for (int r = 0; r < 4; ++r) red[g - 1][r][c] = acc[r];
    }
    __syncthreads();
    if (g == 0) {
        #pragma unroll
        for (int r = 0; r < 4; ++r) {
            acc[r] += red[0][r][c] + red[1][r][c] + red[2][r][c];
            h2[(b * NN + r0 + r) * FIN + c] = acc[r];
        }
        const int lane = t & 63, w2v = t >> 6;
        const float as = as2[c], ad = ad2[c];
        #pragma unroll
        for (int r = 0; r < 4; ++r) {
            float s = acc[r] * as, dd = acc[r] * ad;
            #pragma unroll
            for (int off = 32; off > 0; off >>= 1) {
                s += __shfl_down(s, off, 64);
                dd += __shfl_down(dd, off, 64);
            }
            if (lane == 0) { redS[r][w2v] = s; redD[r][w2v] = dd; }
        }
    }
    __syncthreads();
    if (t < 4) {
        a_src[b * NN + r0 + t] = redS[t][0] + redS[t][1];
        a_dst[b * NN + r0 + t] = redD[t][0] + redD[t][1];
    }
}

// ---------------- K4: layer-2 softmax + aggregate + bias --------------------
// grid (64, 8), block 512. 4 dsts/block; srcs 4-way split; spT b128 reads.
__global__ __launch_bounds__(512, 4)
void agg2_kernel(const float* __restrict__ h2, const float* __restrict__ a_src,
                 const float* __restrict__ a_dst, const float* __restrict__ b2,
                 float* __restrict__ out) {
    __shared__ float s_as[NN];
    __shared__ float s_ad[4];
    __shared__ float spT[NN][8];            // 8 KB, stride 8 (32B, aligned)
    __shared__ float redm[4][2], reds[4][2];
    __shared__ float s_den[4];
    __shared__ float redA[3][4][FIN];       // 6 KB

    const int b = blockIdx.y, d0 = blockIdx.x * 4, t = threadIdx.x;

    if (t < NN) s_as[t] = a_src[b * NN + t];
    if (t < 4) s_ad[t] = a_dst[b * NN + d0 + t];
    __syncthreads();

    // softmax: 128-thread group per dst.
    const int d = t >> 7, l = t & 127, lane = t & 63, w = (t >> 6) & 1;
    const float adst = s_ad[d];
    float e0 = lrelu(s_as[l] + adst);
    float e1 = lrelu(s_as[l + 128] + adst);
    float mx = fmaxf(e0, e1);
    #pragma unroll
    for (int off = 32; off > 0; off >>= 1)
        mx = fmaxf(mx, __shfl_down(mx, off, 64));
    if (lane == 0) redm[d][w] = mx;
    __syncthreads();
    const float m = fmaxf(redm[d][0], redm[d][1]);
    float p0 = __expf(e0 - m), p1 = __expf(e1 - m);
    spT[l][d] = p0;
    spT[l + 128][d] = p1;
    float sum = p0 + p1;
    #pragma unroll
    for (int off = 32; off > 0; off >>= 1)
        sum += __shfl_down(sum, off, 64);
    if (lane == 0) reds[d][w] = sum;
    __syncthreads();
    if (t < 4) s_den[t] = reds[t][0] + reds[t][1] + 1e-16f;
    __syncthreads();

    // aggregation: q = src-quarter; 4 dsts per thread; 1 b128 spT read per src.
    const int c = l, q = d;
    float a4[4] = {0.f, 0.f, 0.f, 0.f};
    const float* hb = h2 + ((size_t)(b * NN) + q * 64) * FIN + c;
    #pragma unroll 4
    for (int i = 0; i < 64; ++i) {
        float hv = hb[(size_t)i * FIN];
        float4 p4 = *(const float4*)&spT[q * 64 + i][0];
        a4[0] = fmaf(p4.x, hv, a4[0]);
        a4[1] = fmaf(p4.y, hv, a4[1]);
        a4[2] = fmaf(p4.z, hv, a4[2]);
        a4[3] = fmaf(p4.w, hv, a4[3]);
    }
    if (q > 0) {
        #pragma unroll
        for (int j = 0; j < 4; ++j) redA[q - 1][j][c] = a4[j];
    }
    __syncthreads();
    if (q == 0) {
        #pragma unroll
        for (int j = 0; j < 4; ++j) {
            float v = a4[j] + redA[0][j][c] + redA[1][j][c] + redA[2][j][c];
            out[(b * NN + d0 + j) * FIN + c] = v / s_den[j] + b2[c];
        }
    }
}

// ---------------- launch -----------------------------------------------------
extern "C" void kernel_launch(void* const* d_in, const int* in_sizes, int n_in,
                              void* d_out, int out_size, void* d_ws, size_t ws_size,
                              hipStream_t stream) {
    const float* x   = (const float*)d_in[0];
    const float* W1  = (const float*)d_in[1];
    const float* as1 = (const float*)d_in[2];
    const float* ad1 = (const float*)d_in[3];
    const float* b1  = (const float*)d_in[4];
    const float* W2  = (const float*)d_in[5];
    const float* as2 = (const float*)d_in[6];
    const float* ad2 = (const float*)d_in[7];
    const float* b2  = (const float*)d_in[8];
    float* out = (float*)d_out;

    float* ws = (float*)d_ws;
    float* h1     = ws;                      // 8*256*512 = 1048576
    float* hrelu  = ws + 1048576;            // 1048576
    float* h2     = ws + 2097152;            // 262144
    float* a_src1 = ws + 2359296;            // 8192
    float* a_dst1 = ws + 2367488;            // 8192
    float* a_src2 = ws + 2375680;            // 2048
    float* a_dst2 = ws + 2377728;            // 2048

    gemm1_fused<<<dim3(32, BATCH), 256, 0, stream>>>(x, W1, as1, ad1, h1, a_src1, a_dst1);
    agg1_kernel<<<dim3(16, H1, BATCH), 512, 0, stream>>>(h1, a_src1, a_dst1, b1, hrelu);
    gemm2_fused<<<dim3(64, BATCH), 512, 0, stream>>>(hrelu, W2, as2, ad2, h2, a_src2, a_dst2);
    agg2_kernel<<<dim3(64, BATCH), 512, 0, stream>>>(h2, a_src2, a_dst2, b2, out);
}

// Round 9
// 117.690 us; speedup vs baseline: 1.0969x; 1.0969x over previous
//
#include <hip/hip_runtime.h>
#include <hip/hip_bf16.h>

#define BATCH 8
#define NN    256
#define FIN   128
#define H1    4
#define C1    128
#define HC1   512   // H1*C1
#define NEG_SLOPE 0.2f

__device__ __forceinline__ float lrelu(float v) {
    return v > 0.f ? v : NEG_SLOPE * v;
}

// ---------------- K_A: h1 = x @ W1, fused a_src1/a_dst1 (r6-proven) ---------
// grid (64, 8), block 512. Block: 4 rows x 512 cols. 4 FMA per W1 load.
__global__ __launch_bounds__(512, 4)
void gemm1_fused(const float* __restrict__ x, const float* __restrict__ W1,
                 const float* __restrict__ as1, const float* __restrict__ ad1,
                 float* __restrict__ h1, float* __restrict__ a_src,
                 float* __restrict__ a_dst) {
    __shared__ float xs[4][FIN];
    __shared__ float redS[4][8], redD[4][8];
    const int b = blockIdx.y, r0 = blockIdx.x * 4, t = threadIdx.x;

    if (t < 128)   // 4 rows x 128 = 128 float4, coalesced
        ((float4*)xs)[t] = ((const float4*)(x + (size_t)(b * NN + r0) * FIN))[t];
    __syncthreads();

    float a0 = 0.f, a1 = 0.f, a2 = 0.f, a3 = 0.f;
    #pragma unroll 8
    for (int k = 0; k < FIN; ++k) {
        float w = W1[k * HC1 + t];
        a0 = fmaf(xs[0][k], w, a0);
        a1 = fmaf(xs[1][k], w, a1);
        a2 = fmaf(xs[2][k], w, a2);
        a3 = fmaf(xs[3][k], w, a3);
    }
    float acc[4] = {a0, a1, a2, a3};
    #pragma unroll
    for (int r = 0; r < 4; ++r)
        h1[(b * NN + r0 + r) * HC1 + t] = acc[r];

    // fused a-reductions: col t -> head t>>7; att vectors are flat [512].
    const float as = as1[t], ad = ad1[t];
    const int w = t >> 6, lane = t & 63;
    #pragma unroll
    for (int r = 0; r < 4; ++r) {
        float s = acc[r] * as, d = acc[r] * ad;
        #pragma unroll
        for (int off = 32; off > 0; off >>= 1) {
            s += __shfl_down(s, off, 64);
            d += __shfl_down(d, off, 64);
        }
        if (lane == 0) { redS[r][w] = s; redD[r][w] = d; }
    }
    __syncthreads();
    if (t < 16) {   // wave w covers cols [64w,64w+63] -> head w>>1
        int r = t & 3, h = t >> 2;
        a_src[(b * NN + r0 + r) * H1 + h] = redS[r][2 * h] + redS[r][2 * h + 1];
        a_dst[(b * NN + r0 + r) * H1 + h] = redD[r][2 * h] + redD[r][2 * h + 1];
    }
}

// ---------------- K_B: agg1 (all heads) + relu + gemm2 + ared2 fused --------
// grid (32 dst-tiles of 8, 8 batch), block 512. hrelu never leaves LDS.
__global__ __launch_bounds__(512, 2)
void mid_fused(const float* __restrict__ h1, const float* __restrict__ a_src,
               const float* __restrict__ a_dst, const float* __restrict__ b1,
               const float* __restrict__ W2, const float* __restrict__ as2,
               const float* __restrict__ ad2, float* __restrict__ h2,
               float* __restrict__ a_src2, float* __restrict__ a_dst2) {
    __shared__ __align__(16) float s_as[H1][NN];      // 4 KB
    __shared__ float s_ad[H1][8];
    __shared__ __align__(16) float spT[NN][36];       // 36 KB: p[src][h*8+d], stride 36
    __shared__ float s_den[32];
    __shared__ __align__(16) float hrelu_s[8][HC1];   // 16 KB
    __shared__ float red[3][8][FIN];                  // 12 KB
    __shared__ float redS[8][2], redD[8][2];

    const int b = blockIdx.y, d0 = blockIdx.x * 8, t = threadIdx.x;

    // stage a_src (all heads, all nodes) and a_dst (8 dsts x 4 heads)
    {
        int i0 = t, i1 = t + 512;                     // 1024 = 4*256
        ((float*)s_as)[ (i0 >> 8) * NN + (i0 & 255) ] = a_src[(b * NN + (i0 & 255)) * H1 + (i0 >> 8)];
        ((float*)s_as)[ (i1 >> 8) * NN + (i1 & 255) ] = a_src[(b * NN + (i1 & 255)) * H1 + (i1 >> 8)];
        if (t < 32) {
            int h = t >> 3, d = t & 7;
            s_ad[h][d] = a_dst[(b * NN + d0 + d) * H1 + h];
        }
    }
    __syncthreads();

    // softmax: 32 (head,dst) pairs x 16 threads; each thread 16 srcs.
    {
        const int pair = t >> 4, sub = t & 15;
        const int h = pair >> 3, d = pair & 7;
        const float adst = s_ad[h][d];
        float e[16];
        float mx = -1e30f;
        #pragma unroll
        for (int i = 0; i < 16; ++i) {
            float v = lrelu(s_as[h][sub + i * 16] + adst);
            e[i] = v;
            mx = fmaxf(mx, v);
        }
        #pragma unroll
        for (int off = 8; off > 0; off >>= 1)
            mx = fmaxf(mx, __shfl_down(mx, off, 16));
        mx = __shfl(mx, 0, 16);
        float sum = 0.f;
        #pragma unroll
        for (int i = 0; i < 16; ++i) {
            float p = __expf(e[i] - mx);
            spT[sub + i * 16][pair] = p;
            sum += p;
        }
        #pragma unroll
        for (int off = 8; off > 0; off >>= 1)
            sum += __shfl_down(sum, off, 16);
        if (sub == 0) s_den[pair] = sum + 1e-16f;
    }
    __syncthreads();

    // agg1: thread t -> full col ct (h = ct>>7); 8 dsts; 1 coalesced h1 load/src.
    {
        const int ct = t, h = t >> 7;
        float acc8[8] = {0,0,0,0,0,0,0,0};
        const float* hb = h1 + (size_t)(b * NN) * HC1 + ct;
        #pragma unroll 4
        for (int src = 0; src < NN; ++src) {
            float hv = hb[(size_t)src * HC1];
            float4 pa = *(const float4*)&spT[src][h * 8];
            float4 pb = *(const float4*)&spT[src][h * 8 + 4];
            acc8[0] = fmaf(pa.x, hv, acc8[0]);
            acc8[1] = fmaf(pa.y, hv, acc8[1]);
            acc8[2] = fmaf(pa.z, hv, acc8[2]);
            acc8[3] = fmaf(pa.w, hv, acc8[3]);
            acc8[4] = fmaf(pb.x, hv, acc8[4]);
            acc8[5] = fmaf(pb.y, hv, acc8[5]);
            acc8[6] = fmaf(pb.z, hv, acc8[6]);
            acc8[7] = fmaf(pb.w, hv, acc8[7]);
        }
        const float bias = b1[ct];
        #pragma unroll
        for (int d = 0; d < 8; ++d)
            hrelu_s[d][ct] = fmaxf(acc8[d] / s_den[h * 8 + d] + bias, 0.f);
    }
    __syncthreads();

    // gemm2: K split 4-way (g), 8 rows x 128 cols; float4 LDS reads.
    const int c2 = t & 127, g = t >> 7;
    float acc[8] = {0,0,0,0,0,0,0,0};
    {
        const float* wb = W2 + (size_t)(g * 128) * FIN + c2;
        #pragma unroll 2
        for (int kq = 0; kq < 32; ++kq) {
            float w0 = wb[(size_t)(kq * 4 + 0) * FIN];
            float w1 = wb[(size_t)(kq * 4 + 1) * FIN];
            float w2 = wb[(size_t)(kq * 4 + 2) * FIN];
            float w3 = wb[(size_t)(kq * 4 + 3) * FIN];
            #pragma unroll
            for (int r = 0; r < 8; ++r) {
                float4 xv = *(const float4*)&hrelu_s[r][g * 128 + kq * 4];
                acc[r] = fmaf(xv.x, w0, acc[r]);
                acc[r] = fmaf(xv.y, w1, acc[r]);
                acc[r] = fmaf(xv.z, w2, acc[r]);
                acc[r] = fmaf(xv.w, w3, acc[r]);
            }
        }
    }
    if (g > 0) {
        #pragma unroll
        for (int r = 0; r < 8; ++r) red[g - 1][r][c2] = acc[r];
    }
    __syncthreads();
    if (g == 0) {
        #pragma unroll
        for (int r = 0; r < 8; ++r) {
            acc[r] += red[0][r][c2] + red[1][r][c2] + red[2][r][c2];
            h2[(b * NN + d0 + r) * FIN + c2] = acc[r];
        }
        // ared2: reduce over c2 (128 threads = 2 waves) per row.
        const int lane = t & 63, wv = t >> 6;
        const float as = as2[c2], ad = ad2[c2];
        #pragma unroll
        for (int r = 0; r < 8; ++r) {
            float s = acc[r] * as, dd = acc[r] * ad;
            #pragma unroll
            for (int off = 32; off > 0; off >>= 1) {
                s += __shfl_down(s, off, 64);
                dd += __shfl_down(dd, off, 64);
            }
            if (lane == 0) { redS[r][wv] = s; redD[r][wv] = dd; }
        }
    }
    __syncthreads();
    if (t < 8) {
        a_src2[b * NN + d0 + t] = redS[t][0] + redS[t][1];
        a_dst2[b * NN + d0 + t] = redD[t][0] + redD[t][1];
    }
}

// ---------------- K_C: layer-2 softmax + aggregate + bias (r6-proven) -------
// grid (64, 8), block 512. 4 dsts/block; agg splits srcs 4-way (q), 4 FMA/load.
__global__ __launch_bounds__(512, 4)
void agg2_kernel(const float* __restrict__ h2, const float* __restrict__ a_src,
                 const float* __restrict__ a_dst, const float* __restrict__ b2,
                 float* __restrict__ out) {
    __shared__ float s_as[NN];
    __shared__ float s_ad[4];
    __shared__ float sp[4][NN];
    __shared__ float redm[4][2], reds[4][2];
    __shared__ float s_den[4];
    __shared__ float redA[3][4][FIN];       // 6 KB

    const int b = blockIdx.y, d0 = blockIdx.x * 4, t = threadIdx.x;

    if (t < NN) s_as[t] = a_src[b * NN + t];
    if (t < 4) s_ad[t] = a_dst[b * NN + d0 + t];
    __syncthreads();

    // softmax: 128-thread group per dst.
    const int d = t >> 7, l = t & 127, lane = t & 63, w = (t >> 6) & 1;
    const float adst = s_ad[d];
    float e0 = lrelu(s_as[l] + adst);
    float e1 = lrelu(s_as[l + 128] + adst);
    float mx = fmaxf(e0, e1);
    #pragma unroll
    for (int off = 32; off > 0; off >>= 1)
        mx = fmaxf(mx, __shfl_down(mx, off, 64));
    if (lane == 0) redm[d][w] = mx;
    __syncthreads();
    const float m = fmaxf(redm[d][0], redm[d][1]);
    float p0 = __expf(e0 - m), p1 = __expf(e1 - m);
    sp[d][l] = p0;
    sp[d][l + 128] = p1;
    float sum = p0 + p1;
    #pragma unroll
    for (int off = 32; off > 0; off >>= 1)
        sum += __shfl_down(sum, off, 64);
    if (lane == 0) reds[d][w] = sum;
    __syncthreads();
    if (t < 4) s_den[t] = reds[t][0] + reds[t][1] + 1e-16f;
    __syncthreads();

    // aggregation: q = src-quarter; all 4 dsts per thread -> 4 FMA per load.
    const int c = l, q = d;
    float a4[4] = {0.f, 0.f, 0.f, 0.f};
    const float* hb = h2 + ((size_t)(b * NN) + q * 64) * FIN + c;
    #pragma unroll 8
    for (int i = 0; i < 64; ++i) {
        float hv = hb[(size_t)i * FIN];
        int src = q * 64 + i;
        a4[0] = fmaf(sp[0][src], hv, a4[0]);
        a4[1] = fmaf(sp[1][src], hv, a4[1]);
        a4[2] = fmaf(sp[2][src], hv, a4[2]);
        a4[3] = fmaf(sp[3][src], hv, a4[3]);
    }
    if (q > 0) {
        #pragma unroll
        for (int j = 0; j < 4; ++j) redA[q - 1][j][c] = a4[j];
    }
    __syncthreads();
    if (q == 0) {
        #pragma unroll
        for (int j = 0; j < 4; ++j) {
            float v = a4[j] + redA[0][j][c] + redA[1][j][c] + redA[2][j][c];
            out[(b * NN + d0 + j) * FIN + c] = v / s_den[j] + b2[c];
        }
    }
}

// ---------------- launch -----------------------------------------------------
extern "C" void kernel_launch(void* const* d_in, const int* in_sizes, int n_in,
                              void* d_out, int out_size, void* d_ws, size_t ws_size,
                              hipStream_t stream) {
    const float* x   = (const float*)d_in[0];
    const float* W1  = (const float*)d_in[1];
    const float* as1 = (const float*)d_in[2];
    const float* ad1 = (const float*)d_in[3];
    const float* b1  = (const float*)d_in[4];
    const float* W2  = (const float*)d_in[5];
    const float* as2 = (const float*)d_in[6];
    const float* ad2 = (const float*)d_in[7];
    const float* b2  = (const float*)d_in[8];
    float* out = (float*)d_out;

    float* ws = (float*)d_ws;
    float* h1     = ws;                      // 8*256*512 = 1048576
    float* h2     = ws + 1048576;            // 262144
    float* a_src1 = ws + 1310720;            // 8192
    float* a_dst1 = ws + 1318912;            // 8192
    float* a_src2 = ws + 1327104;            // 2048
    float* a_dst2 = ws + 1329152;            // 2048

    gemm1_fused<<<dim3(64, BATCH), 512, 0, stream>>>(x, W1, as1, ad1, h1, a_src1, a_dst1);
    mid_fused<<<dim3(32, BATCH), 512, 0, stream>>>(h1, a_src1, a_dst1, b1, W2, as2, ad2,
                                                   h2, a_src2, a_dst2);
    agg2_kernel<<<dim3(64, BATCH), 512, 0, stream>>>(h2, a_src2, a_dst2, b2, out);
}